// Round 4
// baseline (574.206 us; speedup 1.0000x reference)
//
#include <hip/hip_runtime.h>

#define NTOT 2048
#define INF 64
#define HD 256
#define EHD 128
#define ONF 64
#define NL 4

typedef __attribute__((ext_vector_type(8))) short bf16x8;
typedef __attribute__((ext_vector_type(4))) float f32x4;

__device__ __forceinline__ float silu_f(float v) {
    return v * __builtin_amdgcn_rcpf(1.0f + __expf(-v));
}

// rounded split (weights, one-time)
__device__ __forceinline__ unsigned short f2bf_rn(float f) {
    unsigned u = __float_as_uint(f);
    u += 0x7FFFu + ((u >> 16) & 1u);
    return (unsigned short)(u >> 16);
}
__device__ __forceinline__ void split_rn(float v, unsigned short& h, unsigned short& l) {
    h = f2bf_rn(v);
    l = f2bf_rn(v - __uint_as_float((unsigned)h << 16));
}
// truncating split (activations): uh/ul are top-16-masked uints (bf16 in high half)
__device__ __forceinline__ void split_tr(float v, unsigned& uh, unsigned& ul) {
    unsigned u = __float_as_uint(v);
    uh = u & 0xffff0000u;
    ul = __float_as_uint(v - __uint_as_float(uh)) & 0xffff0000u;
}
__device__ __forceinline__ float bfraw2f(unsigned short s) {
    return __uint_as_float((unsigned)s << 16);
}

// ================= weight fragment prep (one launch, all matrices) =================
// frag layout per matrix: slot = (nt*KS + ks)*64 + lane; elem i: W[k][n],
// n = nt*16 + (lane&15), k = ks*32 + (lane>>4)*8 + i
__global__ __launch_bounds__(256) void k_prep(
        const float* __restrict__ w_in, const float* __restrict__ we1,
        const float* __restrict__ wn1, const float* __restrict__ wn2,
        const float* __restrict__ w_out, const float* __restrict__ we2,
        short* __restrict__ hwin, short* __restrict__ lwin,
        short* __restrict__ hwe1, short* __restrict__ lwe1,
        short* __restrict__ hwn1, short* __restrict__ lwn1,
        short* __restrict__ hwn2, short* __restrict__ lwn2,
        short* __restrict__ hwout, short* __restrict__ lwout,
        short* __restrict__ hwe2, short* __restrict__ lwe2) {
    const int gid = blockIdx.x * 256 + threadIdx.x;
    const float* src; short* hd; short* ld;
    int sl, dst, KS, N, mode;
    if (gid < 2048)        { sl = gid;                dst = gid;           src = w_in;                                  hd = hwin;  ld = lwin;  KS = 2;  N = 256; mode = 0; }
    else if (gid < 34816)  { int g = gid - 2048;      sl = g & 8191;  dst = g; src = we1 + (size_t)(g >> 13) * 512 * 128;   hd = hwe1;  ld = lwe1;  KS = 8;  N = 256; mode = 1; }
    else if (gid < 83968)  { int g = gid - 34816;     sl = g % 12288; dst = g; src = wn1 + (size_t)(g / 12288) * 384 * 256; hd = hwn1;  ld = lwn1;  KS = 12; N = 256; mode = 0; }
    else if (gid < 116736) { int g = gid - 83968;     sl = g & 8191;  dst = g; src = wn2 + (size_t)(g >> 13) * 256 * 256;   hd = hwn2;  ld = lwn2;  KS = 8;  N = 256; mode = 0; }
    else if (gid < 118784) { int g = gid - 116736;    sl = g;         dst = g; src = w_out;                                 hd = hwout; ld = lwout; KS = 8;  N = 64;  mode = 0; }
    else if (gid < 126976) { int g = gid - 118784;    sl = g & 2047;  dst = g; src = we2 + (size_t)(g >> 11) * 128 * 128;   hd = hwe2;  ld = lwe2;  KS = 4;  N = 128; mode = 0; }
    else return;
    const int lane = sl & 63;
    const int t2 = sl >> 6;
    const int ks = t2 % KS;
    const int nt = t2 / KS;
    const int n = nt * 16 + (lane & 15);
    const int k0 = ks * 32 + ((lane >> 4) << 3);
    short h8[8], l8[8];
#pragma unroll
    for (int i = 0; i < 8; ++i) {
        int k = k0 + i;
        float f;
        if (mode == 1) f = (n < 128) ? src[(size_t)k * 128 + n] : src[(size_t)(256 + k) * 128 + (n - 128)];
        else           f = src[(size_t)k * N + n];
        unsigned short hh, ll;
        split_rn(f, hh, ll);
        h8[i] = (short)hh; l8[i] = (short)ll;
    }
#pragma unroll
    for (int i = 0; i < 8; ++i) {
        hd[(size_t)dst * 8 + i] = h8[i];
        ld[(size_t)dst * 8 + i] = l8[i];
    }
}

// ================= embed + layer-0 A/B, fused MFMA (1024 thr / 16 waves) =================
__global__ __launch_bounds__(1024, 4) void k_embed_ab(
        const float* __restrict__ h, const float* __restrict__ b_in,
        const float* __restrict__ be1,
        const short* __restrict__ hwin, const short* __restrict__ lwin,
        const short* __restrict__ hwe1, const short* __restrict__ lwe1,
        short* __restrict__ xs_hi, short* __restrict__ xs_lo,
        float* __restrict__ A, float* __restrict__ Bb) {
    __shared__ __align__(16) short hls[2][2][64][8];
    __shared__ __align__(16) short xls[2][8][64][8];
    const int t = threadIdx.x;
    const int mt = blockIdx.x;
    const int n0 = mt * 16;
    const int w = t >> 6, lane = t & 63;
    const int r0 = (lane >> 4) * 4;

    // stage h rows -> split frags in LDS (coalesced: lane sweeps k)
    {
        const int m = t >> 6, k = t & 63;
        float v = h[(size_t)(n0 + m) * INF + k];
        unsigned uh, ul;
        split_tr(v, uh, ul);
        const int ks = k >> 5;
        const int lane2 = m + 16 * ((k & 31) >> 3);
        const int i0 = k & 7;
        hls[0][ks][lane2][i0] = (short)(uh >> 16);
        hls[1][ks][lane2][i0] = (short)(ul >> 16);
    }
    __syncthreads();
    // GEMM0: x = h @ w_in   (wave w -> nt = w)
    f32x4 acc = {0.f, 0.f, 0.f, 0.f};
#pragma unroll
    for (int ks = 0; ks < 2; ++ks) {
        bf16x8 ah = *(const bf16x8*)&hls[0][ks][lane][0];
        bf16x8 al = *(const bf16x8*)&hls[1][ks][lane][0];
        bf16x8 bh = ((const bf16x8*)hwin)[(w * 2 + ks) * 64 + lane];
        bf16x8 bl = ((const bf16x8*)lwin)[(w * 2 + ks) * 64 + lane];
        acc = __builtin_amdgcn_mfma_f32_16x16x32_bf16(ah, bh, acc, 0, 0, 0);
        acc = __builtin_amdgcn_mfma_f32_16x16x32_bf16(al, bh, acc, 0, 0, 0);
        acc = __builtin_amdgcn_mfma_f32_16x16x32_bf16(ah, bl, acc, 0, 0, 0);
    }
    // epilogue0: x = acc + b_in -> split into xls
    {
        int col = w * 16 + (lane & 15);
        float bias = b_in[col];
        int ks = col >> 5, l2b = 16 * ((col & 31) >> 3), i2 = col & 7;
#pragma unroll
        for (int reg = 0; reg < 4; ++reg) {
            float xv = acc[reg] + bias;
            unsigned uh, ul;
            split_tr(xv, uh, ul);
            xls[0][ks][r0 + reg + l2b][i2] = (short)(uh >> 16);
            xls[1][ks][r0 + reg + l2b][i2] = (short)(ul >> 16);
        }
    }
    __syncthreads();
    // dump xls -> xs global (1024 slots, 1 rep)
    {
        int s = t;
        int plane = s >> 9, ks = (s >> 6) & 7, ln = s & 63;
        bf16x8 v = *(const bf16x8*)&xls[plane][ks][ln][0];
        bf16x8* dstp = (bf16x8*)(plane ? xs_lo : xs_hi);
        dstp[(size_t)(mt * 8 + ks) * 64 + ln] = v;
    }
    // GEMM1: [A|B] = x @ we1[0]   (wave w -> nt = w)
    f32x4 acc1 = {0.f, 0.f, 0.f, 0.f};
#pragma unroll
    for (int ks = 0; ks < 8; ++ks) {
        bf16x8 ah = *(const bf16x8*)&xls[0][ks][lane][0];
        bf16x8 al = *(const bf16x8*)&xls[1][ks][lane][0];
        bf16x8 bh = ((const bf16x8*)hwe1)[(w * 8 + ks) * 64 + lane];
        bf16x8 bl = ((const bf16x8*)lwe1)[(w * 8 + ks) * 64 + lane];
        acc1 = __builtin_amdgcn_mfma_f32_16x16x32_bf16(ah, bh, acc1, 0, 0, 0);
        acc1 = __builtin_amdgcn_mfma_f32_16x16x32_bf16(al, bh, acc1, 0, 0, 0);
        acc1 = __builtin_amdgcn_mfma_f32_16x16x32_bf16(ah, bl, acc1, 0, 0, 0);
    }
    {
        int j = w * 16 + (lane & 15);
        float bias = (j < 128) ? be1[j] : 0.0f;
        float* dstp = (j < 128) ? A : Bb;
        int jj = j & 127;
#pragma unroll
        for (int reg = 0; reg < 4; ++reg) {
            int node = n0 + r0 + reg;
            dstp[(size_t)node * 128 + jj] = acc1[reg] + bias;
        }
    }
}

// ================= edge GEMM + scatter-sum, MFMA =================
__global__ __launch_bounds__(256, 6) void k_edge_mfma(
        const float* __restrict__ A, const float* __restrict__ Bb,
        const short* __restrict__ hwe2, const short* __restrict__ lwe2,
        const float* __restrict__ be2, float* __restrict__ agg) {
    __shared__ __align__(16) short fr[2][2][4][64][8];  // [copy][mt][ks][lane][i]
    const int n = blockIdx.x;
    const int b0 = n & ~127;
    const int r = n & 127;
    const int t = threadIdx.x;
    const int w = t >> 6;
    const int lane = t & 63;
    const int kg = t & 15;
    const int ksw = kg >> 2;
    const int lanef = ((kg & 3) << 4);

    float a8[8];
    {
        const float4 a0 = *(const float4*)&A[(size_t)n * EHD + kg * 8];
        const float4 a1 = *(const float4*)&A[(size_t)n * EHD + kg * 8 + 4];
        a8[0] = a0.x; a8[1] = a0.y; a8[2] = a0.z; a8[3] = a0.w;
        a8[4] = a1.x; a8[5] = a1.y; a8[6] = a1.z; a8[7] = a1.w;
    }
    bf16x8 bh[2][4], bl[2][4];
#pragma unroll
    for (int nti = 0; nti < 2; ++nti) {
        const int nt = w * 2 + nti;
#pragma unroll
        for (int ks = 0; ks < 4; ++ks) {
            bh[nti][ks] = ((const bf16x8*)hwe2)[(nt * 4 + ks) * 64 + lane];
            bl[nti][ks] = ((const bf16x8*)lwe2)[(nt * 4 + ks) * 64 + lane];
        }
    }
    float be2v[2];
#pragma unroll
    for (int nti = 0; nti < 2; ++nti)
        be2v[nti] = be2[(w * 2 + nti) * 16 + (lane & 15)];

    float colsum[2] = {0.0f, 0.0f};

    for (int ch = 0; ch < 4; ++ch) {
        __syncthreads();
#pragma unroll
        for (int iter = 0; iter < 2; ++iter) {
            const int c_l = iter * 16 + (t >> 4);
            const int mtl = c_l >> 4;
            const float* Brow = &Bb[(size_t)(b0 + ch * 32 + c_l) * EHD + kg * 8];
            const float4 bv0 = *(const float4*)Brow;
            const float4 bv1 = *(const float4*)(Brow + 4);
            float v[8] = {bv0.x + a8[0], bv0.y + a8[1], bv0.z + a8[2], bv0.w + a8[3],
                          bv1.x + a8[4], bv1.y + a8[5], bv1.z + a8[6], bv1.w + a8[7]};
            unsigned uh[8], ul[8];
#pragma unroll
            for (int i = 0; i < 8; ++i) {
                float s = silu_f(v[i]);
                split_tr(s, uh[i], ul[i]);
            }
            uint4 ph, pl;
            ph.x = (uh[0] >> 16) | uh[1]; ph.y = (uh[2] >> 16) | uh[3];
            ph.z = (uh[4] >> 16) | uh[5]; ph.w = (uh[6] >> 16) | uh[7];
            pl.x = (ul[0] >> 16) | ul[1]; pl.y = (ul[2] >> 16) | ul[3];
            pl.z = (ul[4] >> 16) | ul[5]; pl.w = (ul[6] >> 16) | ul[7];
            const int lf = lanef + (c_l & 15);
            *(uint4*)&fr[0][mtl][ksw][lf][0] = ph;
            *(uint4*)&fr[1][mtl][ksw][lf][0] = pl;
        }
        __syncthreads();
#pragma unroll
        for (int mtl = 0; mtl < 2; ++mtl) {
            bf16x8 ah[4], al[4];
#pragma unroll
            for (int ks = 0; ks < 4; ++ks) {
                ah[ks] = *(const bf16x8*)&fr[0][mtl][ks][lane][0];
                al[ks] = *(const bf16x8*)&fr[1][mtl][ks][lane][0];
            }
#pragma unroll
            for (int nti = 0; nti < 2; ++nti) {
                f32x4 acc = {0.0f, 0.0f, 0.0f, 0.0f};
#pragma unroll
                for (int ks = 0; ks < 4; ++ks) {
                    acc = __builtin_amdgcn_mfma_f32_16x16x32_bf16(ah[ks], bh[nti][ks], acc, 0, 0, 0);
                    acc = __builtin_amdgcn_mfma_f32_16x16x32_bf16(al[ks], bh[nti][ks], acc, 0, 0, 0);
                    acc = __builtin_amdgcn_mfma_f32_16x16x32_bf16(ah[ks], bl[nti][ks], acc, 0, 0, 0);
                }
                const int cbase = ch * 32 + mtl * 16 + ((lane >> 4) << 2);
#pragma unroll
                for (int reg = 0; reg < 4; ++reg) {
                    const int c = cbase + reg;
                    float s = silu_f(acc[reg] + be2v[nti]);
                    if (c != r) colsum[nti] += s;
                }
            }
        }
    }
#pragma unroll
    for (int nti = 0; nti < 2; ++nti) {
        float s = colsum[nti];
        s += __shfl_xor(s, 16);
        s += __shfl_xor(s, 32);
        if (lane < 16)
            agg[(size_t)n * EHD + (w * 2 + nti) * 16 + lane] = s;
    }
}

// ================= node MLP + residual + next-layer A/B (or final out), 1024 thr / 16 waves =================
__global__ __launch_bounds__(1024, 4) void k_node_ab(
        const float* __restrict__ agg,
        const float* __restrict__ bn1, const float* __restrict__ bn2,
        const float* __restrict__ be1, const float* __restrict__ b_out,
        const short* __restrict__ hwn1, const short* __restrict__ lwn1,
        const short* __restrict__ hwn2, const short* __restrict__ lwn2,
        const short* __restrict__ hwe1, const short* __restrict__ lwe1,
        const short* __restrict__ hwout, const short* __restrict__ lwout,
        short* __restrict__ xs_hi, short* __restrict__ xs_lo,
        float* __restrict__ A, float* __restrict__ Bb,
        float* __restrict__ outp, int last) {
    __shared__ __align__(16) short cat[2][12][64][8];  // 24KB  [x | agg] frags
    __shared__ __align__(16) short u1[2][8][64][8];    // 16KB
    __shared__ __align__(16) short xn[2][8][64][8];    // 16KB
    const int t = threadIdx.x;
    const int mt = blockIdx.x;
    const int n0 = mt * 16;
    const int w = t >> 6, lane = t & 63;
    const int r0 = (lane >> 4) * 4;

    // stage x frags (pure copy from xs): 1024 slots, 1 rep
    {
        int s = t;
        int plane = s >> 9, ks = (s >> 6) & 7, ln = s & 63;
        const bf16x8* srcp = (const bf16x8*)(plane ? xs_lo : xs_hi);
        bf16x8 v = srcp[(size_t)(mt * 8 + ks) * 64 + ln];
        *(bf16x8*)&cat[plane][ks][ln][0] = v;
    }
    // stage agg rows -> frags at ks 8..11 (coalesced: lane sweeps k)
    {
        const int m = t >> 6;
        const int kq = t & 63;
        const int k0 = kq * 2;
        const float2 v2 = *(const float2*)&agg[(size_t)(n0 + m) * EHD + k0];
        unsigned uh0, ul0, uh1, ul1;
        split_tr(v2.x, uh0, ul0);
        split_tr(v2.y, uh1, ul1);
        const int ks = 8 + (k0 >> 5);
        const int lane2 = m + 16 * ((k0 & 31) >> 3);
        const int i0 = k0 & 7;
        *(unsigned*)&cat[0][ks][lane2][i0] = (uh0 >> 16) | uh1;
        *(unsigned*)&cat[1][ks][lane2][i0] = (ul0 >> 16) | ul1;
    }
    __syncthreads();
    // GEMM1: pre = cat @ wn1[l]  (K=384, wave w -> nt = w)
    f32x4 acc = {0.f, 0.f, 0.f, 0.f};
#pragma unroll
    for (int ks = 0; ks < 12; ++ks) {
        bf16x8 ah = *(const bf16x8*)&cat[0][ks][lane][0];
        bf16x8 al = *(const bf16x8*)&cat[1][ks][lane][0];
        bf16x8 bh = ((const bf16x8*)hwn1)[(w * 12 + ks) * 64 + lane];
        bf16x8 bl = ((const bf16x8*)lwn1)[(w * 12 + ks) * 64 + lane];
        acc = __builtin_amdgcn_mfma_f32_16x16x32_bf16(ah, bh, acc, 0, 0, 0);
        acc = __builtin_amdgcn_mfma_f32_16x16x32_bf16(al, bh, acc, 0, 0, 0);
        acc = __builtin_amdgcn_mfma_f32_16x16x32_bf16(ah, bl, acc, 0, 0, 0);
    }
    // epilogue1: u1 = silu(pre + bn1)
    const int col = w * 16 + (lane & 15);
    const int ksu = col >> 5, l2b = 16 * ((col & 31) >> 3), i2 = col & 7;
    {
        float bias = bn1[col];
#pragma unroll
        for (int reg = 0; reg < 4; ++reg) {
            float uv = silu_f(acc[reg] + bias);
            unsigned uh, ul;
            split_tr(uv, uh, ul);
            u1[0][ksu][r0 + reg + l2b][i2] = (short)(uh >> 16);
            u1[1][ksu][r0 + reg + l2b][i2] = (short)(ul >> 16);
        }
    }
    __syncthreads();
    // GEMM2: pre2 = u1 @ wn2[l]  (K=256)
    f32x4 acc2 = {0.f, 0.f, 0.f, 0.f};
#pragma unroll
    for (int ks = 0; ks < 8; ++ks) {
        bf16x8 ah = *(const bf16x8*)&u1[0][ks][lane][0];
        bf16x8 al = *(const bf16x8*)&u1[1][ks][lane][0];
        bf16x8 bh = ((const bf16x8*)hwn2)[(w * 8 + ks) * 64 + lane];
        bf16x8 bl = ((const bf16x8*)lwn2)[(w * 8 + ks) * 64 + lane];
        acc2 = __builtin_amdgcn_mfma_f32_16x16x32_bf16(ah, bh, acc2, 0, 0, 0);
        acc2 = __builtin_amdgcn_mfma_f32_16x16x32_bf16(al, bh, acc2, 0, 0, 0);
        acc2 = __builtin_amdgcn_mfma_f32_16x16x32_bf16(ah, bl, acc2, 0, 0, 0);
    }
    // epilogue2: xnew = pre2 + bn2 + x_old
    {
        float bias = bn2[col];
#pragma unroll
        for (int reg = 0; reg < 4; ++reg) {
            int lane2 = r0 + reg + l2b;
            float xold = bfraw2f((unsigned short)cat[0][ksu][lane2][i2])
                       + bfraw2f((unsigned short)cat[1][ksu][lane2][i2]);
            float xv = acc2[reg] + bias + xold;
            unsigned uh, ul;
            split_tr(xv, uh, ul);
            xn[0][ksu][lane2][i2] = (short)(uh >> 16);
            xn[1][ksu][lane2][i2] = (short)(ul >> 16);
        }
    }
    __syncthreads();
    if (!last) {
        // dump xn -> xs (1024 slots)
        {
            int s = t;
            int plane = s >> 9, ks = (s >> 6) & 7, ln = s & 63;
            bf16x8 v = *(const bf16x8*)&xn[plane][ks][ln][0];
            bf16x8* dstp = (bf16x8*)(plane ? xs_lo : xs_hi);
            dstp[(size_t)(mt * 8 + ks) * 64 + ln] = v;
        }
        // GEMM3: [A|B] = xnew @ we1[l+1]  (wave w -> nt = w)
        f32x4 acc3 = {0.f, 0.f, 0.f, 0.f};
#pragma unroll
        for (int ks = 0; ks < 8; ++ks) {
            bf16x8 ah = *(const bf16x8*)&xn[0][ks][lane][0];
            bf16x8 al = *(const bf16x8*)&xn[1][ks][lane][0];
            bf16x8 bh = ((const bf16x8*)hwe1)[(w * 8 + ks) * 64 + lane];
            bf16x8 bl = ((const bf16x8*)lwe1)[(w * 8 + ks) * 64 + lane];
            acc3 = __builtin_amdgcn_mfma_f32_16x16x32_bf16(ah, bh, acc3, 0, 0, 0);
            acc3 = __builtin_amdgcn_mfma_f32_16x16x32_bf16(al, bh, acc3, 0, 0, 0);
            acc3 = __builtin_amdgcn_mfma_f32_16x16x32_bf16(ah, bl, acc3, 0, 0, 0);
        }
        {
            int j = col;
            float bias = (j < 128) ? be1[j] : 0.0f;
            float* dstp = (j < 128) ? A : Bb;
            int jj = j & 127;
#pragma unroll
            for (int reg = 0; reg < 4; ++reg) {
                int node = n0 + r0 + reg;
                dstp[(size_t)node * 128 + jj] = acc3[reg] + bias;
            }
        }
    } else if (w < 4) {
        // GEMM_out: out = xnew @ w_out + b_out  (N=64: waves 0..3, nt=w)
        f32x4 acco = {0.f, 0.f, 0.f, 0.f};
#pragma unroll
        for (int ks = 0; ks < 8; ++ks) {
            bf16x8 ah = *(const bf16x8*)&xn[0][ks][lane][0];
            bf16x8 al = *(const bf16x8*)&xn[1][ks][lane][0];
            bf16x8 bh = ((const bf16x8*)hwout)[(w * 8 + ks) * 64 + lane];
            bf16x8 bl = ((const bf16x8*)lwout)[(w * 8 + ks) * 64 + lane];
            acco = __builtin_amdgcn_mfma_f32_16x16x32_bf16(ah, bh, acco, 0, 0, 0);
            acco = __builtin_amdgcn_mfma_f32_16x16x32_bf16(al, bh, acco, 0, 0, 0);
            acco = __builtin_amdgcn_mfma_f32_16x16x32_bf16(ah, bl, acco, 0, 0, 0);
        }
        float bias = b_out[col];
#pragma unroll
        for (int reg = 0; reg < 4; ++reg) {
            outp[(size_t)(n0 + r0 + reg) * ONF + col] = acco[reg] + bias;
        }
    }
}

extern "C" void kernel_launch(void* const* d_in, const int* in_sizes, int n_in,
                              void* d_out, int out_size, void* d_ws, size_t ws_size,
                              hipStream_t stream) {
    const float* h     = (const float*)d_in[0];
    const float* w_in  = (const float*)d_in[3];
    const float* b_in  = (const float*)d_in[4];
    const float* w_out = (const float*)d_in[5];
    const float* b_out = (const float*)d_in[6];
    const float* we1   = (const float*)d_in[7];
    const float* be1   = (const float*)d_in[8];
    const float* we2   = (const float*)d_in[9];
    const float* be2   = (const float*)d_in[10];
    const float* wn1   = (const float*)d_in[11];
    const float* bn1   = (const float*)d_in[12];
    const float* wn2   = (const float*)d_in[13];
    const float* bn2   = (const float*)d_in[14];

    float* A    = (float*)d_ws;              // 2048*128
    float* Bb   = A + 262144;                // 2048*128
    float* agg  = Bb + 262144;               // 2048*128
    short* xs_hi = (short*)(agg + 262144);   // 2048*256
    short* xs_lo = xs_hi + 524288;
    short* hwin  = xs_lo + 524288;           // 2048*8
    short* lwin  = hwin + 16384;
    short* hwe1  = lwin + 16384;             // 4*8192*8
    short* lwe1  = hwe1 + 262144;
    short* hwn1  = lwe1 + 262144;            // 4*12288*8
    short* lwn1  = hwn1 + 393216;
    short* hwn2  = lwn1 + 393216;            // 4*8192*8
    short* lwn2  = hwn2 + 262144;
    short* hwout = lwn2 + 262144;            // 2048*8
    short* lwout = hwout + 16384;
    short* hwe2  = lwout + 16384;            // 4*2048*8
    short* lwe2  = hwe2 + 65536;
    float* outp  = (float*)d_out;

    k_prep<<<496, 256, 0, stream>>>(w_in, we1, wn1, wn2, w_out, we2,
        hwin, lwin, hwe1, lwe1, hwn1, lwn1, hwn2, lwn2, hwout, lwout, hwe2, lwe2);
    k_embed_ab<<<128, 1024, 0, stream>>>(h, b_in, be1, hwin, lwin, hwe1, lwe1,
        xs_hi, xs_lo, A, Bb);
    for (int l = 0; l < NL; ++l) {
        const int last = (l == NL - 1);
        const int lp = last ? 0 : (l + 1);
        k_edge_mfma<<<NTOT, 256, 0, stream>>>(A, Bb,
            hwe2 + (size_t)l * 2048 * 8, lwe2 + (size_t)l * 2048 * 8,
            be2 + l * EHD, agg);
        k_node_ab<<<128, 1024, 0, stream>>>(agg,
            bn1 + l * HD, bn2 + l * HD, be1 + lp * EHD, b_out,
            hwn1 + (size_t)l * 12288 * 8, lwn1 + (size_t)l * 12288 * 8,
            hwn2 + (size_t)l * 8192 * 8, lwn2 + (size_t)l * 8192 * 8,
            hwe1 + (size_t)lp * 8192 * 8, lwe1 + (size_t)lp * 8192 * 8,
            hwout, lwout, xs_hi, xs_lo, A, Bb, outp, last);
    }
}

// Round 5
// 170.416 us; speedup vs baseline: 3.3694x; 3.3694x over previous
//
#include <hip/hip_runtime.h>

#define NTOT 2048
#define INF 64
#define HD 256
#define EHD 128
#define ONF 64
#define NL 4

typedef __attribute__((ext_vector_type(8))) short bf16x8;
typedef __attribute__((ext_vector_type(4))) float f32x4;

__device__ __forceinline__ float silu_f(float v) {
    return v * __builtin_amdgcn_rcpf(1.0f + __expf(-v));
}

// rounded bf16
__device__ __forceinline__ unsigned short f2bf_rn(float f) {
    unsigned u = __float_as_uint(f);
    u += 0x7FFFu + ((u >> 16) & 1u);
    return (unsigned short)(u >> 16);
}
__device__ __forceinline__ void split_rn(float v, unsigned short& h, unsigned short& l) {
    h = f2bf_rn(v);
    l = f2bf_rn(v - __uint_as_float((unsigned)h << 16));
}
// truncating split (activations): uh/ul are top-16-masked uints (bf16 in high half)
__device__ __forceinline__ void split_tr(float v, unsigned& uh, unsigned& ul) {
    unsigned u = __float_as_uint(v);
    uh = u & 0xffff0000u;
    ul = __float_as_uint(v - __uint_as_float(uh)) & 0xffff0000u;
}
__device__ __forceinline__ float bfraw2f(unsigned short s) {
    return __uint_as_float((unsigned)s << 16);
}

// ================= weight fragment prep (one launch, all matrices) =================
// frag layout per matrix: slot = (nt*KS + ks)*64 + lane; elem i: W[k][n],
// n = nt*16 + (lane&15), k = ks*32 + (lane>>4)*8 + i
__global__ __launch_bounds__(256) void k_prep(
        const float* __restrict__ w_in, const float* __restrict__ we1,
        const float* __restrict__ wn1, const float* __restrict__ wn2,
        const float* __restrict__ w_out, const float* __restrict__ we2,
        short* __restrict__ hwin, short* __restrict__ lwin,
        short* __restrict__ hwe1, short* __restrict__ lwe1,
        short* __restrict__ hwn1, short* __restrict__ lwn1,
        short* __restrict__ hwn2, short* __restrict__ lwn2,
        short* __restrict__ hwout, short* __restrict__ lwout,
        short* __restrict__ hwe2, short* __restrict__ lwe2) {
    const int gid = blockIdx.x * 256 + threadIdx.x;
    const float* src; short* hd; short* ld;
    int sl, dst, KS, N, mode;
    if (gid < 2048)        { sl = gid;                dst = gid;           src = w_in;                                  hd = hwin;  ld = lwin;  KS = 2;  N = 256; mode = 0; }
    else if (gid < 34816)  { int g = gid - 2048;      sl = g & 8191;  dst = g; src = we1 + (size_t)(g >> 13) * 512 * 128;   hd = hwe1;  ld = lwe1;  KS = 8;  N = 256; mode = 1; }
    else if (gid < 83968)  { int g = gid - 34816;     sl = g % 12288; dst = g; src = wn1 + (size_t)(g / 12288) * 384 * 256; hd = hwn1;  ld = lwn1;  KS = 12; N = 256; mode = 0; }
    else if (gid < 116736) { int g = gid - 83968;     sl = g & 8191;  dst = g; src = wn2 + (size_t)(g >> 13) * 256 * 256;   hd = hwn2;  ld = lwn2;  KS = 8;  N = 256; mode = 0; }
    else if (gid < 118784) { int g = gid - 116736;    sl = g;         dst = g; src = w_out;                                 hd = hwout; ld = lwout; KS = 8;  N = 64;  mode = 0; }
    else if (gid < 126976) { int g = gid - 118784;    sl = g & 2047;  dst = g; src = we2 + (size_t)(g >> 11) * 128 * 128;   hd = hwe2;  ld = lwe2;  KS = 4;  N = 128; mode = 0; }
    else return;
    const int lane = sl & 63;
    const int t2 = sl >> 6;
    const int ks = t2 % KS;
    const int nt = t2 / KS;
    const int n = nt * 16 + (lane & 15);
    const int k0 = ks * 32 + ((lane >> 4) << 3);
    short h8[8], l8[8];
#pragma unroll
    for (int i = 0; i < 8; ++i) {
        int k = k0 + i;
        float f;
        if (mode == 1) f = (n < 128) ? src[(size_t)k * 128 + n] : src[(size_t)(256 + k) * 128 + (n - 128)];
        else           f = src[(size_t)k * N + n];
        unsigned short hh, ll;
        split_rn(f, hh, ll);
        h8[i] = (short)hh; l8[i] = (short)ll;
    }
#pragma unroll
    for (int i = 0; i < 8; ++i) {
        hd[(size_t)dst * 8 + i] = h8[i];
        ld[(size_t)dst * 8 + i] = l8[i];
    }
}

// ================= embed + layer-0 A/B, fused MFMA (1024 thr / 16 waves) =================
__global__ __launch_bounds__(1024, 4) void k_embed_ab(
        const float* __restrict__ h, const float* __restrict__ b_in,
        const float* __restrict__ be1,
        const short* __restrict__ hwin, const short* __restrict__ lwin,
        const short* __restrict__ hwe1, const short* __restrict__ lwe1,
        short* __restrict__ xs_hi, short* __restrict__ xs_lo,
        float* __restrict__ A, float* __restrict__ Bb) {
    __shared__ __align__(16) short hls[2][2][64][8];
    __shared__ __align__(16) short xls[2][8][64][8];
    const int t = threadIdx.x;
    const int mt = blockIdx.x;
    const int n0 = mt * 16;
    const int w = t >> 6, lane = t & 63;
    const int r0 = (lane >> 4) * 4;

    // stage h rows -> split frags in LDS (coalesced: lane sweeps k)
    {
        const int m = t >> 6, k = t & 63;
        float v = h[(size_t)(n0 + m) * INF + k];
        unsigned uh, ul;
        split_tr(v, uh, ul);
        const int ks = k >> 5;
        const int lane2 = m + 16 * ((k & 31) >> 3);
        const int i0 = k & 7;
        hls[0][ks][lane2][i0] = (short)(uh >> 16);
        hls[1][ks][lane2][i0] = (short)(ul >> 16);
    }
    __syncthreads();
    // GEMM0: x = h @ w_in   (wave w -> nt = w)
    f32x4 acc = {0.f, 0.f, 0.f, 0.f};
#pragma unroll
    for (int ks = 0; ks < 2; ++ks) {
        bf16x8 ah = *(const bf16x8*)&hls[0][ks][lane][0];
        bf16x8 al = *(const bf16x8*)&hls[1][ks][lane][0];
        bf16x8 bh = ((const bf16x8*)hwin)[(w * 2 + ks) * 64 + lane];
        bf16x8 bl = ((const bf16x8*)lwin)[(w * 2 + ks) * 64 + lane];
        acc = __builtin_amdgcn_mfma_f32_16x16x32_bf16(ah, bh, acc, 0, 0, 0);
        acc = __builtin_amdgcn_mfma_f32_16x16x32_bf16(al, bh, acc, 0, 0, 0);
        acc = __builtin_amdgcn_mfma_f32_16x16x32_bf16(ah, bl, acc, 0, 0, 0);
    }
    // epilogue0: x = acc + b_in -> split into xls
    {
        int col = w * 16 + (lane & 15);
        float bias = b_in[col];
        int ks = col >> 5, l2b = 16 * ((col & 31) >> 3), i2 = col & 7;
#pragma unroll
        for (int reg = 0; reg < 4; ++reg) {
            float xv = acc[reg] + bias;
            unsigned uh, ul;
            split_tr(xv, uh, ul);
            xls[0][ks][r0 + reg + l2b][i2] = (short)(uh >> 16);
            xls[1][ks][r0 + reg + l2b][i2] = (short)(ul >> 16);
        }
    }
    __syncthreads();
    // dump xls -> xs global (1024 slots, 1 rep)
    {
        int s = t;
        int plane = s >> 9, ks = (s >> 6) & 7, ln = s & 63;
        bf16x8 v = *(const bf16x8*)&xls[plane][ks][ln][0];
        bf16x8* dstp = (bf16x8*)(plane ? xs_lo : xs_hi);
        dstp[(size_t)(mt * 8 + ks) * 64 + ln] = v;
    }
    // GEMM1: [A|B] = x @ we1[0]   (wave w -> nt = w)
    f32x4 acc1 = {0.f, 0.f, 0.f, 0.f};
#pragma unroll
    for (int ks = 0; ks < 8; ++ks) {
        bf16x8 ah = *(const bf16x8*)&xls[0][ks][lane][0];
        bf16x8 al = *(const bf16x8*)&xls[1][ks][lane][0];
        bf16x8 bh = ((const bf16x8*)hwe1)[(w * 8 + ks) * 64 + lane];
        bf16x8 bl = ((const bf16x8*)lwe1)[(w * 8 + ks) * 64 + lane];
        acc1 = __builtin_amdgcn_mfma_f32_16x16x32_bf16(ah, bh, acc1, 0, 0, 0);
        acc1 = __builtin_amdgcn_mfma_f32_16x16x32_bf16(al, bh, acc1, 0, 0, 0);
        acc1 = __builtin_amdgcn_mfma_f32_16x16x32_bf16(ah, bl, acc1, 0, 0, 0);
    }
    {
        int j = w * 16 + (lane & 15);
        float bias = (j < 128) ? be1[j] : 0.0f;
        float* dstp = (j < 128) ? A : Bb;
        int jj = j & 127;
#pragma unroll
        for (int reg = 0; reg < 4; ++reg) {
            int node = n0 + r0 + reg;
            dstp[(size_t)node * 128 + jj] = acc1[reg] + bias;
        }
    }
}

// ================= edge GEMM + scatter-sum, single-bf16 MFMA =================
__global__ __launch_bounds__(256, 4) void k_edge_mfma(
        const float* __restrict__ A, const float* __restrict__ Bb,
        const short* __restrict__ hwe2,
        const float* __restrict__ be2, float* __restrict__ agg) {
    __shared__ __align__(16) short fr[2][4][64][8];  // [mt][ks][lane][i] rounded bf16
    const int n = blockIdx.x;
    const int b0 = n & ~127;
    const int r = n & 127;
    const int t = threadIdx.x;
    const int w = t >> 6;
    const int lane = t & 63;
    const int kg = t & 15;
    const int ksw = kg >> 2;
    const int lanef = ((kg & 3) << 4);

    float a8[8];
    {
        const float4 a0 = *(const float4*)&A[(size_t)n * EHD + kg * 8];
        const float4 a1 = *(const float4*)&A[(size_t)n * EHD + kg * 8 + 4];
        a8[0] = a0.x; a8[1] = a0.y; a8[2] = a0.z; a8[3] = a0.w;
        a8[4] = a1.x; a8[5] = a1.y; a8[6] = a1.z; a8[7] = a1.w;
    }
    bf16x8 bh[2][4];
#pragma unroll
    for (int nti = 0; nti < 2; ++nti) {
        const int nt = w * 2 + nti;
#pragma unroll
        for (int ks = 0; ks < 4; ++ks)
            bh[nti][ks] = ((const bf16x8*)hwe2)[(nt * 4 + ks) * 64 + lane];
    }
    float be2v[2];
#pragma unroll
    for (int nti = 0; nti < 2; ++nti)
        be2v[nti] = be2[(w * 2 + nti) * 16 + (lane & 15)];

    float colsum[2] = {0.0f, 0.0f};

    for (int ch = 0; ch < 4; ++ch) {
        __syncthreads();
        // phase 1: m1 = rn_bf16(silu(A + B[sender])) -> fragments in LDS
#pragma unroll
        for (int iter = 0; iter < 2; ++iter) {
            const int c_l = iter * 16 + (t >> 4);
            const int mtl = c_l >> 4;
            const float* Brow = &Bb[(size_t)(b0 + ch * 32 + c_l) * EHD + kg * 8];
            const float4 bv0 = *(const float4*)Brow;
            const float4 bv1 = *(const float4*)(Brow + 4);
            float v[8] = {bv0.x + a8[0], bv0.y + a8[1], bv0.z + a8[2], bv0.w + a8[3],
                          bv1.x + a8[4], bv1.y + a8[5], bv1.z + a8[6], bv1.w + a8[7]};
            unsigned short rb[8];
#pragma unroll
            for (int i = 0; i < 8; ++i)
                rb[i] = f2bf_rn(silu_f(v[i]));
            uint4 ph;
            ph.x = (unsigned)rb[0] | ((unsigned)rb[1] << 16);
            ph.y = (unsigned)rb[2] | ((unsigned)rb[3] << 16);
            ph.z = (unsigned)rb[4] | ((unsigned)rb[5] << 16);
            ph.w = (unsigned)rb[6] | ((unsigned)rb[7] << 16);
            const int lf = lanef + (c_l & 15);
            *(uint4*)&fr[mtl][ksw][lf][0] = ph;
        }
        __syncthreads();
        // phase 2: MFMA + epilogue
#pragma unroll
        for (int mtl = 0; mtl < 2; ++mtl) {
            bf16x8 ah[4];
#pragma unroll
            for (int ks = 0; ks < 4; ++ks)
                ah[ks] = *(const bf16x8*)&fr[mtl][ks][lane][0];
#pragma unroll
            for (int nti = 0; nti < 2; ++nti) {
                f32x4 acc = {0.0f, 0.0f, 0.0f, 0.0f};
#pragma unroll
                for (int ks = 0; ks < 4; ++ks)
                    acc = __builtin_amdgcn_mfma_f32_16x16x32_bf16(ah[ks], bh[nti][ks], acc, 0, 0, 0);
                const int cbase = ch * 32 + mtl * 16 + ((lane >> 4) << 2);
#pragma unroll
                for (int reg = 0; reg < 4; ++reg) {
                    const int c = cbase + reg;
                    float s = silu_f(acc[reg] + be2v[nti]);
                    if (c != r) colsum[nti] += s;
                }
            }
        }
    }
#pragma unroll
    for (int nti = 0; nti < 2; ++nti) {
        float s = colsum[nti];
        s += __shfl_xor(s, 16);
        s += __shfl_xor(s, 32);
        if (lane < 16)
            agg[(size_t)n * EHD + (w * 2 + nti) * 16 + lane] = s;
    }
}

// ================= node MLP + residual + next-layer A/B (or final out), 1024 thr / 16 waves =================
__global__ __launch_bounds__(1024, 4) void k_node_ab(
        const float* __restrict__ agg,
        const float* __restrict__ bn1, const float* __restrict__ bn2,
        const float* __restrict__ be1, const float* __restrict__ b_out,
        const short* __restrict__ hwn1, const short* __restrict__ lwn1,
        const short* __restrict__ hwn2, const short* __restrict__ lwn2,
        const short* __restrict__ hwe1, const short* __restrict__ lwe1,
        const short* __restrict__ hwout, const short* __restrict__ lwout,
        short* __restrict__ xs_hi, short* __restrict__ xs_lo,
        float* __restrict__ A, float* __restrict__ Bb,
        float* __restrict__ outp, int last) {
    __shared__ __align__(16) short cat[2][12][64][8];  // 24KB  [x | agg] frags
    __shared__ __align__(16) short u1[2][8][64][8];    // 16KB
    __shared__ __align__(16) short xn[2][8][64][8];    // 16KB
    const int t = threadIdx.x;
    const int mt = blockIdx.x;
    const int n0 = mt * 16;
    const int w = t >> 6, lane = t & 63;
    const int r0 = (lane >> 4) * 4;

    // stage x frags (pure copy from xs): 1024 slots, 1 rep
    {
        int s = t;
        int plane = s >> 9, ks = (s >> 6) & 7, ln = s & 63;
        const bf16x8* srcp = (const bf16x8*)(plane ? xs_lo : xs_hi);
        bf16x8 v = srcp[(size_t)(mt * 8 + ks) * 64 + ln];
        *(bf16x8*)&cat[plane][ks][ln][0] = v;
    }
    // stage agg rows -> frags at ks 8..11 (coalesced: lane sweeps k)
    {
        const int m = t >> 6;
        const int kq = t & 63;
        const int k0 = kq * 2;
        const float2 v2 = *(const float2*)&agg[(size_t)(n0 + m) * EHD + k0];
        unsigned uh0, ul0, uh1, ul1;
        split_tr(v2.x, uh0, ul0);
        split_tr(v2.y, uh1, ul1);
        const int ks = 8 + (k0 >> 5);
        const int lane2 = m + 16 * ((k0 & 31) >> 3);
        const int i0 = k0 & 7;
        *(unsigned*)&cat[0][ks][lane2][i0] = (uh0 >> 16) | uh1;
        *(unsigned*)&cat[1][ks][lane2][i0] = (ul0 >> 16) | ul1;
    }
    __syncthreads();
    // GEMM1: pre = cat @ wn1[l]  (K=384, wave w -> nt = w)
    f32x4 acc = {0.f, 0.f, 0.f, 0.f};
#pragma unroll
    for (int ks = 0; ks < 12; ++ks) {
        bf16x8 ah = *(const bf16x8*)&cat[0][ks][lane][0];
        bf16x8 al = *(const bf16x8*)&cat[1][ks][lane][0];
        bf16x8 bh = ((const bf16x8*)hwn1)[(w * 12 + ks) * 64 + lane];
        bf16x8 bl = ((const bf16x8*)lwn1)[(w * 12 + ks) * 64 + lane];
        acc = __builtin_amdgcn_mfma_f32_16x16x32_bf16(ah, bh, acc, 0, 0, 0);
        acc = __builtin_amdgcn_mfma_f32_16x16x32_bf16(al, bh, acc, 0, 0, 0);
        acc = __builtin_amdgcn_mfma_f32_16x16x32_bf16(ah, bl, acc, 0, 0, 0);
    }
    // epilogue1: u1 = silu(pre + bn1)
    const int col = w * 16 + (lane & 15);
    const int ksu = col >> 5, l2b = 16 * ((col & 31) >> 3), i2 = col & 7;
    {
        float bias = bn1[col];
#pragma unroll
        for (int reg = 0; reg < 4; ++reg) {
            float uv = silu_f(acc[reg] + bias);
            unsigned uh, ul;
            split_tr(uv, uh, ul);
            u1[0][ksu][r0 + reg + l2b][i2] = (short)(uh >> 16);
            u1[1][ksu][r0 + reg + l2b][i2] = (short)(ul >> 16);
        }
    }
    __syncthreads();
    // GEMM2: pre2 = u1 @ wn2[l]  (K=256)
    f32x4 acc2 = {0.f, 0.f, 0.f, 0.f};
#pragma unroll
    for (int ks = 0; ks < 8; ++ks) {
        bf16x8 ah = *(const bf16x8*)&u1[0][ks][lane][0];
        bf16x8 al = *(const bf16x8*)&u1[1][ks][lane][0];
        bf16x8 bh = ((const bf16x8*)hwn2)[(w * 8 + ks) * 64 + lane];
        bf16x8 bl = ((const bf16x8*)lwn2)[(w * 8 + ks) * 64 + lane];
        acc2 = __builtin_amdgcn_mfma_f32_16x16x32_bf16(ah, bh, acc2, 0, 0, 0);
        acc2 = __builtin_amdgcn_mfma_f32_16x16x32_bf16(al, bh, acc2, 0, 0, 0);
        acc2 = __builtin_amdgcn_mfma_f32_16x16x32_bf16(ah, bl, acc2, 0, 0, 0);
    }
    // epilogue2: xnew = pre2 + bn2 + x_old
    {
        float bias = bn2[col];
#pragma unroll
        for (int reg = 0; reg < 4; ++reg) {
            int lane2 = r0 + reg + l2b;
            float xold = bfraw2f((unsigned short)cat[0][ksu][lane2][i2])
                       + bfraw2f((unsigned short)cat[1][ksu][lane2][i2]);
            float xv = acc2[reg] + bias + xold;
            unsigned uh, ul;
            split_tr(xv, uh, ul);
            xn[0][ksu][lane2][i2] = (short)(uh >> 16);
            xn[1][ksu][lane2][i2] = (short)(ul >> 16);
        }
    }
    __syncthreads();
    if (!last) {
        // dump xn -> xs (1024 slots)
        {
            int s = t;
            int plane = s >> 9, ks = (s >> 6) & 7, ln = s & 63;
            bf16x8 v = *(const bf16x8*)&xn[plane][ks][ln][0];
            bf16x8* dstp = (bf16x8*)(plane ? xs_lo : xs_hi);
            dstp[(size_t)(mt * 8 + ks) * 64 + ln] = v;
        }
        // GEMM3: [A|B] = xnew @ we1[l+1]  (wave w -> nt = w)
        f32x4 acc3 = {0.f, 0.f, 0.f, 0.f};
#pragma unroll
        for (int ks = 0; ks < 8; ++ks) {
            bf16x8 ah = *(const bf16x8*)&xn[0][ks][lane][0];
            bf16x8 al = *(const bf16x8*)&xn[1][ks][lane][0];
            bf16x8 bh = ((const bf16x8*)hwe1)[(w * 8 + ks) * 64 + lane];
            bf16x8 bl = ((const bf16x8*)lwe1)[(w * 8 + ks) * 64 + lane];
            acc3 = __builtin_amdgcn_mfma_f32_16x16x32_bf16(ah, bh, acc3, 0, 0, 0);
            acc3 = __builtin_amdgcn_mfma_f32_16x16x32_bf16(al, bh, acc3, 0, 0, 0);
            acc3 = __builtin_amdgcn_mfma_f32_16x16x32_bf16(ah, bl, acc3, 0, 0, 0);
        }
        {
            int j = col;
            float bias = (j < 128) ? be1[j] : 0.0f;
            float* dstp = (j < 128) ? A : Bb;
            int jj = j & 127;
#pragma unroll
            for (int reg = 0; reg < 4; ++reg) {
                int node = n0 + r0 + reg;
                dstp[(size_t)node * 128 + jj] = acc3[reg] + bias;
            }
        }
    } else if (w < 4) {
        // GEMM_out: out = xnew @ w_out + b_out  (N=64: waves 0..3, nt=w)
        f32x4 acco = {0.f, 0.f, 0.f, 0.f};
#pragma unroll
        for (int ks = 0; ks < 8; ++ks) {
            bf16x8 ah = *(const bf16x8*)&xn[0][ks][lane][0];
            bf16x8 al = *(const bf16x8*)&xn[1][ks][lane][0];
            bf16x8 bh = ((const bf16x8*)hwout)[(w * 8 + ks) * 64 + lane];
            bf16x8 bl = ((const bf16x8*)lwout)[(w * 8 + ks) * 64 + lane];
            acco = __builtin_amdgcn_mfma_f32_16x16x32_bf16(ah, bh, acco, 0, 0, 0);
            acco = __builtin_amdgcn_mfma_f32_16x16x32_bf16(al, bh, acco, 0, 0, 0);
            acco = __builtin_amdgcn_mfma_f32_16x16x32_bf16(ah, bl, acco, 0, 0, 0);
        }
        float bias = b_out[col];
#pragma unroll
        for (int reg = 0; reg < 4; ++reg) {
            outp[(size_t)(n0 + r0 + reg) * ONF + col] = acco[reg] + bias;
        }
    }
}

extern "C" void kernel_launch(void* const* d_in, const int* in_sizes, int n_in,
                              void* d_out, int out_size, void* d_ws, size_t ws_size,
                              hipStream_t stream) {
    const float* h     = (const float*)d_in[0];
    const float* w_in  = (const float*)d_in[3];
    const float* b_in  = (const float*)d_in[4];
    const float* w_out = (const float*)d_in[5];
    const float* b_out = (const float*)d_in[6];
    const float* we1   = (const float*)d_in[7];
    const float* be1   = (const float*)d_in[8];
    const float* we2   = (const float*)d_in[9];
    const float* be2   = (const float*)d_in[10];
    const float* wn1   = (const float*)d_in[11];
    const float* bn1   = (const float*)d_in[12];
    const float* wn2   = (const float*)d_in[13];
    const float* bn2   = (const float*)d_in[14];

    float* A    = (float*)d_ws;              // 2048*128
    float* Bb   = A + 262144;                // 2048*128
    float* agg  = Bb + 262144;               // 2048*128
    short* xs_hi = (short*)(agg + 262144);   // 2048*256
    short* xs_lo = xs_hi + 524288;
    short* hwin  = xs_lo + 524288;           // 2048*8
    short* lwin  = hwin + 16384;
    short* hwe1  = lwin + 16384;             // 4*8192*8
    short* lwe1  = hwe1 + 262144;
    short* hwn1  = lwe1 + 262144;            // 4*12288*8
    short* lwn1  = hwn1 + 393216;
    short* hwn2  = lwn1 + 393216;            // 4*8192*8
    short* lwn2  = hwn2 + 262144;
    short* hwout = lwn2 + 262144;            // 2048*8
    short* lwout = hwout + 16384;
    short* hwe2  = lwout + 16384;            // 4*2048*8
    short* lwe2  = hwe2 + 65536;
    float* outp  = (float*)d_out;

    k_prep<<<496, 256, 0, stream>>>(w_in, we1, wn1, wn2, w_out, we2,
        hwin, lwin, hwe1, lwe1, hwn1, lwn1, hwn2, lwn2, hwout, lwout, hwe2, lwe2);
    k_embed_ab<<<128, 1024, 0, stream>>>(h, b_in, be1, hwin, lwin, hwe1, lwe1,
        xs_hi, xs_lo, A, Bb);
    for (int l = 0; l < NL; ++l) {
        const int last = (l == NL - 1);
        const int lp = last ? 0 : (l + 1);
        k_edge_mfma<<<NTOT, 256, 0, stream>>>(A, Bb,
            hwe2 + (size_t)l * 2048 * 8,
            be2 + l * EHD, agg);
        k_node_ab<<<128, 1024, 0, stream>>>(agg,
            bn1 + l * HD, bn2 + l * HD, be1 + lp * EHD, b_out,
            hwn1 + (size_t)l * 12288 * 8, lwn1 + (size_t)l * 12288 * 8,
            hwn2 + (size_t)l * 8192 * 8, lwn2 + (size_t)l * 8192 * 8,
            hwe1 + (size_t)lp * 8192 * 8, lwe1 + (size_t)lp * 8192 * 8,
            hwout, lwout, xs_hi, xs_lo, A, Bb, outp, last);
    }
}

// Round 6
// 163.624 us; speedup vs baseline: 3.5093x; 1.0415x over previous
//
#include <hip/hip_runtime.h>

#define NTOT 2048
#define INF 64
#define HD 256
#define EHD 128
#define ONF 64
#define NL 4

typedef __attribute__((ext_vector_type(8))) short bf16x8;
typedef __attribute__((ext_vector_type(4))) float f32x4;

__device__ __forceinline__ float silu_f(float v) {
    return v * __builtin_amdgcn_rcpf(1.0f + __expf(-v));
}

// rounded bf16
__device__ __forceinline__ unsigned short f2bf_rn(float f) {
    unsigned u = __float_as_uint(f);
    u += 0x7FFFu + ((u >> 16) & 1u);
    return (unsigned short)(u >> 16);
}
__device__ __forceinline__ void split_rn(float v, unsigned short& h, unsigned short& l) {
    h = f2bf_rn(v);
    l = f2bf_rn(v - __uint_as_float((unsigned)h << 16));
}
// truncating split (activations): uh/ul are top-16-masked uints (bf16 in high half)
__device__ __forceinline__ void split_tr(float v, unsigned& uh, unsigned& ul) {
    unsigned u = __float_as_uint(v);
    uh = u & 0xffff0000u;
    ul = __float_as_uint(v - __uint_as_float(uh)) & 0xffff0000u;
}
__device__ __forceinline__ float bfraw2f(unsigned short s) {
    return __uint_as_float((unsigned)s << 16);
}

// ================= weight fragment prep (one launch, all matrices) =================
// frag layout per matrix: slot = (nt*KS + ks)*64 + lane; elem i: W[k][n],
// n = nt*16 + (lane&15), k = ks*32 + (lane>>4)*8 + i
__global__ __launch_bounds__(256) void k_prep(
        const float* __restrict__ w_in, const float* __restrict__ we1,
        const float* __restrict__ wn1, const float* __restrict__ wn2,
        const float* __restrict__ w_out, const float* __restrict__ we2,
        short* __restrict__ hwin, short* __restrict__ lwin,
        short* __restrict__ hwe1, short* __restrict__ lwe1,
        short* __restrict__ hwn1, short* __restrict__ lwn1,
        short* __restrict__ hwn2, short* __restrict__ lwn2,
        short* __restrict__ hwout, short* __restrict__ lwout,
        short* __restrict__ hwe2) {
    const int gid = blockIdx.x * 256 + threadIdx.x;
    const float* src; short* hd; short* ld;
    int sl, dst, KS, N, mode;
    if (gid < 2048)        { sl = gid;                dst = gid;           src = w_in;                                  hd = hwin;  ld = lwin;  KS = 2;  N = 256; mode = 0; }
    else if (gid < 34816)  { int g = gid - 2048;      sl = g & 8191;  dst = g; src = we1 + (size_t)(g >> 13) * 512 * 128;   hd = hwe1;  ld = lwe1;  KS = 8;  N = 256; mode = 1; }
    else if (gid < 83968)  { int g = gid - 34816;     sl = g % 12288; dst = g; src = wn1 + (size_t)(g / 12288) * 384 * 256; hd = hwn1;  ld = lwn1;  KS = 12; N = 256; mode = 0; }
    else if (gid < 116736) { int g = gid - 83968;     sl = g & 8191;  dst = g; src = wn2 + (size_t)(g >> 13) * 256 * 256;   hd = hwn2;  ld = lwn2;  KS = 8;  N = 256; mode = 0; }
    else if (gid < 118784) { int g = gid - 116736;    sl = g;         dst = g; src = w_out;                                 hd = hwout; ld = lwout; KS = 8;  N = 64;  mode = 0; }
    else if (gid < 126976) { int g = gid - 118784;    sl = g & 2047;  dst = g; src = we2 + (size_t)(g >> 11) * 128 * 128;   hd = hwe2;  ld = 0;     KS = 4;  N = 128; mode = 0; }
    else return;
    const int lane = sl & 63;
    const int t2 = sl >> 6;
    const int ks = t2 % KS;
    const int nt = t2 / KS;
    const int n = nt * 16 + (lane & 15);
    const int k0 = ks * 32 + ((lane >> 4) << 3);
    short h8[8], l8[8];
#pragma unroll
    for (int i = 0; i < 8; ++i) {
        int k = k0 + i;
        float f;
        if (mode == 1) f = (n < 128) ? src[(size_t)k * 128 + n] : src[(size_t)(256 + k) * 128 + (n - 128)];
        else           f = src[(size_t)k * N + n];
        unsigned short hh, ll;
        split_rn(f, hh, ll);
        h8[i] = (short)hh; l8[i] = (short)ll;
    }
#pragma unroll
    for (int i = 0; i < 8; ++i) hd[(size_t)dst * 8 + i] = h8[i];
    if (ld) {
#pragma unroll
        for (int i = 0; i < 8; ++i) ld[(size_t)dst * 8 + i] = l8[i];
    }
}

// ================= embed + layer-0 A/B, fused MFMA (1024 thr / 16 waves) =================
__global__ __launch_bounds__(1024, 4) void k_embed_ab(
        const float* __restrict__ h, const float* __restrict__ b_in,
        const float* __restrict__ be1,
        const short* __restrict__ hwin, const short* __restrict__ lwin,
        const short* __restrict__ hwe1, const short* __restrict__ lwe1,
        short* __restrict__ xs_hi, short* __restrict__ xs_lo,
        float* __restrict__ A, float* __restrict__ Bb) {
    __shared__ __align__(16) short hls[2][2][64][8];
    __shared__ __align__(16) short xls[2][8][64][8];
    const int t = threadIdx.x;
    const int mt = blockIdx.x;
    const int n0 = mt * 16;
    const int w = t >> 6, lane = t & 63;
    const int r0 = (lane >> 4) * 4;

    // stage h rows -> split frags in LDS (coalesced: lane sweeps k)
    {
        const int m = t >> 6, k = t & 63;
        float v = h[(size_t)(n0 + m) * INF + k];
        unsigned uh, ul;
        split_tr(v, uh, ul);
        const int ks = k >> 5;
        const int lane2 = m + 16 * ((k & 31) >> 3);
        const int i0 = k & 7;
        hls[0][ks][lane2][i0] = (short)(uh >> 16);
        hls[1][ks][lane2][i0] = (short)(ul >> 16);
    }
    __syncthreads();
    // GEMM0: x = h @ w_in   (wave w -> nt = w)
    f32x4 acc = {0.f, 0.f, 0.f, 0.f};
#pragma unroll
    for (int ks = 0; ks < 2; ++ks) {
        bf16x8 ah = *(const bf16x8*)&hls[0][ks][lane][0];
        bf16x8 al = *(const bf16x8*)&hls[1][ks][lane][0];
        bf16x8 bh = ((const bf16x8*)hwin)[(w * 2 + ks) * 64 + lane];
        bf16x8 bl = ((const bf16x8*)lwin)[(w * 2 + ks) * 64 + lane];
        acc = __builtin_amdgcn_mfma_f32_16x16x32_bf16(ah, bh, acc, 0, 0, 0);
        acc = __builtin_amdgcn_mfma_f32_16x16x32_bf16(al, bh, acc, 0, 0, 0);
        acc = __builtin_amdgcn_mfma_f32_16x16x32_bf16(ah, bl, acc, 0, 0, 0);
    }
    // epilogue0: x = acc + b_in -> split into xls
    {
        int col = w * 16 + (lane & 15);
        float bias = b_in[col];
        int ks = col >> 5, l2b = 16 * ((col & 31) >> 3), i2 = col & 7;
#pragma unroll
        for (int reg = 0; reg < 4; ++reg) {
            float xv = acc[reg] + bias;
            unsigned uh, ul;
            split_tr(xv, uh, ul);
            xls[0][ks][r0 + reg + l2b][i2] = (short)(uh >> 16);
            xls[1][ks][r0 + reg + l2b][i2] = (short)(ul >> 16);
        }
    }
    __syncthreads();
    // dump xls -> xs global (1024 slots, 1 rep)
    {
        int s = t;
        int plane = s >> 9, ks = (s >> 6) & 7, ln = s & 63;
        bf16x8 v = *(const bf16x8*)&xls[plane][ks][ln][0];
        bf16x8* dstp = (bf16x8*)(plane ? xs_lo : xs_hi);
        dstp[(size_t)(mt * 8 + ks) * 64 + ln] = v;
    }
    // GEMM1: [A|B] = x @ we1[0]   (wave w -> nt = w)
    f32x4 acc1 = {0.f, 0.f, 0.f, 0.f};
#pragma unroll
    for (int ks = 0; ks < 8; ++ks) {
        bf16x8 ah = *(const bf16x8*)&xls[0][ks][lane][0];
        bf16x8 al = *(const bf16x8*)&xls[1][ks][lane][0];
        bf16x8 bh = ((const bf16x8*)hwe1)[(w * 8 + ks) * 64 + lane];
        bf16x8 bl = ((const bf16x8*)lwe1)[(w * 8 + ks) * 64 + lane];
        acc1 = __builtin_amdgcn_mfma_f32_16x16x32_bf16(ah, bh, acc1, 0, 0, 0);
        acc1 = __builtin_amdgcn_mfma_f32_16x16x32_bf16(al, bh, acc1, 0, 0, 0);
        acc1 = __builtin_amdgcn_mfma_f32_16x16x32_bf16(ah, bl, acc1, 0, 0, 0);
    }
    {
        int j = w * 16 + (lane & 15);
        float bias = (j < 128) ? be1[j] : 0.0f;
        float* dstp = (j < 128) ? A : Bb;
        int jj = j & 127;
#pragma unroll
        for (int reg = 0; reg < 4; ++reg) {
            int node = n0 + r0 + reg;
            dstp[(size_t)node * 128 + jj] = acc1[reg] + bias;
        }
    }
}

// ================= edge GEMM + scatter-sum, single-bf16 MFMA, software-pipelined =================
__global__ __launch_bounds__(256, 4) void k_edge_mfma(
        const float* __restrict__ A, const float* __restrict__ Bb,
        const short* __restrict__ hwe2,
        const float* __restrict__ be2, float* __restrict__ agg) {
    __shared__ __align__(16) short fr[2][2][4][64][8];  // [buf][mt][ks][lane][i] rounded bf16
    const int n = blockIdx.x;
    const int b0 = n & ~127;
    const int r = n & 127;
    const int t = threadIdx.x;
    const int w = t >> 6;
    const int lane = t & 63;
    const int kg = t & 15;
    const int ksw = kg >> 2;
    const int lanef = ((kg & 3) << 4);

    float a8[8];
    {
        const float4 a0 = *(const float4*)&A[(size_t)n * EHD + kg * 8];
        const float4 a1 = *(const float4*)&A[(size_t)n * EHD + kg * 8 + 4];
        a8[0] = a0.x; a8[1] = a0.y; a8[2] = a0.z; a8[3] = a0.w;
        a8[4] = a1.x; a8[5] = a1.y; a8[6] = a1.z; a8[7] = a1.w;
    }
    bf16x8 bh[2][4];
#pragma unroll
    for (int nti = 0; nti < 2; ++nti) {
        const int nt = w * 2 + nti;
#pragma unroll
        for (int ks = 0; ks < 4; ++ks)
            bh[nti][ks] = ((const bf16x8*)hwe2)[(nt * 4 + ks) * 64 + lane];
    }
    float be2v[2];
#pragma unroll
    for (int nti = 0; nti < 2; ++nti)
        be2v[nti] = be2[(w * 2 + nti) * 16 + (lane & 15)];

    float colsum[2] = {0.0f, 0.0f};

    // prologue: stage chunk 0 into buf 0
#pragma unroll
    for (int iter = 0; iter < 2; ++iter) {
        const int c_l = iter * 16 + (t >> 4);
        const int mtl = c_l >> 4;
        const float* Brow = &Bb[(size_t)(b0 + c_l) * EHD + kg * 8];
        const float4 bv0 = *(const float4*)Brow;
        const float4 bv1 = *(const float4*)(Brow + 4);
        float v[8] = {bv0.x + a8[0], bv0.y + a8[1], bv0.z + a8[2], bv0.w + a8[3],
                      bv1.x + a8[4], bv1.y + a8[5], bv1.z + a8[6], bv1.w + a8[7]};
        unsigned short rb[8];
#pragma unroll
        for (int i = 0; i < 8; ++i) rb[i] = f2bf_rn(silu_f(v[i]));
        uint4 ph;
        ph.x = (unsigned)rb[0] | ((unsigned)rb[1] << 16);
        ph.y = (unsigned)rb[2] | ((unsigned)rb[3] << 16);
        ph.z = (unsigned)rb[4] | ((unsigned)rb[5] << 16);
        ph.w = (unsigned)rb[6] | ((unsigned)rb[7] << 16);
        *(uint4*)&fr[0][mtl][ksw][lanef + (c_l & 15)][0] = ph;
    }

    for (int ch = 0; ch < 4; ++ch) {
        const int cur = ch & 1;
        __syncthreads();
        // issue next-chunk global loads early (latency hides under MFMA)
        float nv[2][8];
        if (ch < 3) {
#pragma unroll
            for (int iter = 0; iter < 2; ++iter) {
                const int c_l = iter * 16 + (t >> 4);
                const float* Brow = &Bb[(size_t)(b0 + (ch + 1) * 32 + c_l) * EHD + kg * 8];
                const float4 bv0 = *(const float4*)Brow;
                const float4 bv1 = *(const float4*)(Brow + 4);
                nv[iter][0] = bv0.x; nv[iter][1] = bv0.y; nv[iter][2] = bv0.z; nv[iter][3] = bv0.w;
                nv[iter][4] = bv1.x; nv[iter][5] = bv1.y; nv[iter][6] = bv1.z; nv[iter][7] = bv1.w;
            }
        }
        // MFMA cluster from fr[cur]
        f32x4 acc[2][2];
        __builtin_amdgcn_s_setprio(1);
#pragma unroll
        for (int mtl = 0; mtl < 2; ++mtl) {
            bf16x8 ah[4];
#pragma unroll
            for (int ks = 0; ks < 4; ++ks)
                ah[ks] = *(const bf16x8*)&fr[cur][mtl][ks][lane][0];
#pragma unroll
            for (int nti = 0; nti < 2; ++nti) {
                f32x4 a = {0.0f, 0.0f, 0.0f, 0.0f};
#pragma unroll
                for (int ks = 0; ks < 4; ++ks)
                    a = __builtin_amdgcn_mfma_f32_16x16x32_bf16(ah[ks], bh[nti][ks], a, 0, 0, 0);
                acc[mtl][nti] = a;
            }
        }
        __builtin_amdgcn_s_setprio(0);
        // pack + write next chunk into fr[cur^1]
        if (ch < 3) {
#pragma unroll
            for (int iter = 0; iter < 2; ++iter) {
                const int c_l = iter * 16 + (t >> 4);
                const int mtl = c_l >> 4;
                unsigned short rb[8];
#pragma unroll
                for (int i = 0; i < 8; ++i) rb[i] = f2bf_rn(silu_f(nv[iter][i] + a8[i]));
                uint4 ph;
                ph.x = (unsigned)rb[0] | ((unsigned)rb[1] << 16);
                ph.y = (unsigned)rb[2] | ((unsigned)rb[3] << 16);
                ph.z = (unsigned)rb[4] | ((unsigned)rb[5] << 16);
                ph.w = (unsigned)rb[6] | ((unsigned)rb[7] << 16);
                *(uint4*)&fr[cur ^ 1][mtl][ksw][lanef + (c_l & 15)][0] = ph;
            }
        }
        // epilogue: silu + masked colsum
#pragma unroll
        for (int mtl = 0; mtl < 2; ++mtl) {
            const int cbase = ch * 32 + mtl * 16 + ((lane >> 4) << 2);
#pragma unroll
            for (int nti = 0; nti < 2; ++nti) {
#pragma unroll
                for (int reg = 0; reg < 4; ++reg) {
                    const int c = cbase + reg;
                    float s = silu_f(acc[mtl][nti][reg] + be2v[nti]);
                    colsum[nti] += (c != r) ? s : 0.0f;
                }
            }
        }
    }
#pragma unroll
    for (int nti = 0; nti < 2; ++nti) {
        float s = colsum[nti];
        s += __shfl_xor(s, 16);
        s += __shfl_xor(s, 32);
        if (lane < 16)
            agg[(size_t)n * EHD + (w * 2 + nti) * 16 + lane] = s;
    }
}

// ================= node MLP + residual + next-layer A/B (or final out), 1024 thr / 16 waves =================
__global__ __launch_bounds__(1024, 4) void k_node_ab(
        const float* __restrict__ agg,
        const float* __restrict__ bn1, const float* __restrict__ bn2,
        const float* __restrict__ be1, const float* __restrict__ b_out,
        const short* __restrict__ hwn1, const short* __restrict__ lwn1,
        const short* __restrict__ hwn2, const short* __restrict__ lwn2,
        const short* __restrict__ hwe1, const short* __restrict__ lwe1,
        const short* __restrict__ hwout, const short* __restrict__ lwout,
        short* __restrict__ xs_hi, short* __restrict__ xs_lo,
        float* __restrict__ A, float* __restrict__ Bb,
        float* __restrict__ outp, int last) {
    __shared__ __align__(16) short cat[2][12][64][8];  // 24KB  [x | agg] frags
    __shared__ __align__(16) short u1[2][8][64][8];    // 16KB
    __shared__ __align__(16) short xn[2][8][64][8];    // 16KB
    const int t = threadIdx.x;
    const int mt = blockIdx.x;
    const int n0 = mt * 16;
    const int w = t >> 6, lane = t & 63;
    const int r0 = (lane >> 4) * 4;

    // stage x frags (pure copy from xs): 1024 slots, 1 rep
    {
        int s = t;
        int plane = s >> 9, ks = (s >> 6) & 7, ln = s & 63;
        const bf16x8* srcp = (const bf16x8*)(plane ? xs_lo : xs_hi);
        bf16x8 v = srcp[(size_t)(mt * 8 + ks) * 64 + ln];
        *(bf16x8*)&cat[plane][ks][ln][0] = v;
    }
    // stage agg rows -> frags at ks 8..11 (coalesced: lane sweeps k)
    {
        const int m = t >> 6;
        const int kq = t & 63;
        const int k0 = kq * 2;
        const float2 v2 = *(const float2*)&agg[(size_t)(n0 + m) * EHD + k0];
        unsigned uh0, ul0, uh1, ul1;
        split_tr(v2.x, uh0, ul0);
        split_tr(v2.y, uh1, ul1);
        const int ks = 8 + (k0 >> 5);
        const int lane2 = m + 16 * ((k0 & 31) >> 3);
        const int i0 = k0 & 7;
        *(unsigned*)&cat[0][ks][lane2][i0] = (uh0 >> 16) | uh1;
        *(unsigned*)&cat[1][ks][lane2][i0] = (ul0 >> 16) | ul1;
    }
    __syncthreads();
    // GEMM1: pre = cat @ wn1[l]  (K=384, wave w -> nt = w)
    f32x4 acc = {0.f, 0.f, 0.f, 0.f};
#pragma unroll
    for (int ks = 0; ks < 12; ++ks) {
        bf16x8 ah = *(const bf16x8*)&cat[0][ks][lane][0];
        bf16x8 al = *(const bf16x8*)&cat[1][ks][lane][0];
        bf16x8 bh = ((const bf16x8*)hwn1)[(w * 12 + ks) * 64 + lane];
        bf16x8 bl = ((const bf16x8*)lwn1)[(w * 12 + ks) * 64 + lane];
        acc = __builtin_amdgcn_mfma_f32_16x16x32_bf16(ah, bh, acc, 0, 0, 0);
        acc = __builtin_amdgcn_mfma_f32_16x16x32_bf16(al, bh, acc, 0, 0, 0);
        acc = __builtin_amdgcn_mfma_f32_16x16x32_bf16(ah, bl, acc, 0, 0, 0);
    }
    // epilogue1: u1 = silu(pre + bn1)
    const int col = w * 16 + (lane & 15);
    const int ksu = col >> 5, l2b = 16 * ((col & 31) >> 3), i2 = col & 7;
    {
        float bias = bn1[col];
#pragma unroll
        for (int reg = 0; reg < 4; ++reg) {
            float uv = silu_f(acc[reg] + bias);
            unsigned uh, ul;
            split_tr(uv, uh, ul);
            u1[0][ksu][r0 + reg + l2b][i2] = (short)(uh >> 16);
            u1[1][ksu][r0 + reg + l2b][i2] = (short)(ul >> 16);
        }
    }
    __syncthreads();
    // GEMM2: pre2 = u1 @ wn2[l]  (K=256)
    f32x4 acc2 = {0.f, 0.f, 0.f, 0.f};
#pragma unroll
    for (int ks = 0; ks < 8; ++ks) {
        bf16x8 ah = *(const bf16x8*)&u1[0][ks][lane][0];
        bf16x8 al = *(const bf16x8*)&u1[1][ks][lane][0];
        bf16x8 bh = ((const bf16x8*)hwn2)[(w * 8 + ks) * 64 + lane];
        bf16x8 bl = ((const bf16x8*)lwn2)[(w * 8 + ks) * 64 + lane];
        acc2 = __builtin_amdgcn_mfma_f32_16x16x32_bf16(ah, bh, acc2, 0, 0, 0);
        acc2 = __builtin_amdgcn_mfma_f32_16x16x32_bf16(al, bh, acc2, 0, 0, 0);
        acc2 = __builtin_amdgcn_mfma_f32_16x16x32_bf16(ah, bl, acc2, 0, 0, 0);
    }
    // epilogue2: xnew = pre2 + bn2 + x_old
    {
        float bias = bn2[col];
#pragma unroll
        for (int reg = 0; reg < 4; ++reg) {
            int lane2 = r0 + reg + l2b;
            float xold = bfraw2f((unsigned short)cat[0][ksu][lane2][i2])
                       + bfraw2f((unsigned short)cat[1][ksu][lane2][i2]);
            float xv = acc2[reg] + bias + xold;
            unsigned uh, ul;
            split_tr(xv, uh, ul);
            xn[0][ksu][lane2][i2] = (short)(uh >> 16);
            xn[1][ksu][lane2][i2] = (short)(ul >> 16);
        }
    }
    __syncthreads();
    if (!last) {
        // dump xn -> xs (1024 slots)
        {
            int s = t;
            int plane = s >> 9, ks = (s >> 6) & 7, ln = s & 63;
            bf16x8 v = *(const bf16x8*)&xn[plane][ks][ln][0];
            bf16x8* dstp = (bf16x8*)(plane ? xs_lo : xs_hi);
            dstp[(size_t)(mt * 8 + ks) * 64 + ln] = v;
        }
        // GEMM3: [A|B] = xnew @ we1[l+1]  (wave w -> nt = w)
        f32x4 acc3 = {0.f, 0.f, 0.f, 0.f};
#pragma unroll
        for (int ks = 0; ks < 8; ++ks) {
            bf16x8 ah = *(const bf16x8*)&xn[0][ks][lane][0];
            bf16x8 al = *(const bf16x8*)&xn[1][ks][lane][0];
            bf16x8 bh = ((const bf16x8*)hwe1)[(w * 8 + ks) * 64 + lane];
            bf16x8 bl = ((const bf16x8*)lwe1)[(w * 8 + ks) * 64 + lane];
            acc3 = __builtin_amdgcn_mfma_f32_16x16x32_bf16(ah, bh, acc3, 0, 0, 0);
            acc3 = __builtin_amdgcn_mfma_f32_16x16x32_bf16(al, bh, acc3, 0, 0, 0);
            acc3 = __builtin_amdgcn_mfma_f32_16x16x32_bf16(ah, bl, acc3, 0, 0, 0);
        }
        {
            int j = col;
            float bias = (j < 128) ? be1[j] : 0.0f;
            float* dstp = (j < 128) ? A : Bb;
            int jj = j & 127;
#pragma unroll
            for (int reg = 0; reg < 4; ++reg) {
                int node = n0 + r0 + reg;
                dstp[(size_t)node * 128 + jj] = acc3[reg] + bias;
            }
        }
    } else if (w < 4) {
        // GEMM_out: out = xnew @ w_out + b_out  (N=64: waves 0..3, nt=w)
        f32x4 acco = {0.f, 0.f, 0.f, 0.f};
#pragma unroll
        for (int ks = 0; ks < 8; ++ks) {
            bf16x8 ah = *(const bf16x8*)&xn[0][ks][lane][0];
            bf16x8 al = *(const bf16x8*)&xn[1][ks][lane][0];
            bf16x8 bh = ((const bf16x8*)hwout)[(w * 8 + ks) * 64 + lane];
            bf16x8 bl = ((const bf16x8*)lwout)[(w * 8 + ks) * 64 + lane];
            acco = __builtin_amdgcn_mfma_f32_16x16x32_bf16(ah, bh, acco, 0, 0, 0);
            acco = __builtin_amdgcn_mfma_f32_16x16x32_bf16(al, bh, acco, 0, 0, 0);
            acco = __builtin_amdgcn_mfma_f32_16x16x32_bf16(ah, bl, acco, 0, 0, 0);
        }
        float bias = b_out[col];
#pragma unroll
        for (int reg = 0; reg < 4; ++reg) {
            outp[(size_t)(n0 + r0 + reg) * ONF + col] = acco[reg] + bias;
        }
    }
}

extern "C" void kernel_launch(void* const* d_in, const int* in_sizes, int n_in,
                              void* d_out, int out_size, void* d_ws, size_t ws_size,
                              hipStream_t stream) {
    const float* h     = (const float*)d_in[0];
    const float* w_in  = (const float*)d_in[3];
    const float* b_in  = (const float*)d_in[4];
    const float* w_out = (const float*)d_in[5];
    const float* b_out = (const float*)d_in[6];
    const float* we1   = (const float*)d_in[7];
    const float* be1   = (const float*)d_in[8];
    const float* we2   = (const float*)d_in[9];
    const float* be2   = (const float*)d_in[10];
    const float* wn1   = (const float*)d_in[11];
    const float* bn1   = (const float*)d_in[12];
    const float* wn2   = (const float*)d_in[13];
    const float* bn2   = (const float*)d_in[14];

    float* A    = (float*)d_ws;              // 2048*128
    float* Bb   = A + 262144;                // 2048*128
    float* agg  = Bb + 262144;               // 2048*128
    short* xs_hi = (short*)(agg + 262144);   // 2048*256
    short* xs_lo = xs_hi + 524288;
    short* hwin  = xs_lo + 524288;           // 2048*8
    short* lwin  = hwin + 16384;
    short* hwe1  = lwin + 16384;             // 4*8192*8
    short* lwe1  = hwe1 + 262144;
    short* hwn1  = lwe1 + 262144;            // 4*12288*8
    short* lwn1  = hwn1 + 393216;
    short* hwn2  = lwn1 + 393216;            // 4*8192*8
    short* lwn2  = hwn2 + 262144;
    short* hwout = lwn2 + 262144;            // 2048*8
    short* lwout = hwout + 16384;
    short* hwe2  = lwout + 16384;            // 4*2048*8
    float* outp  = (float*)d_out;

    k_prep<<<496, 256, 0, stream>>>(w_in, we1, wn1, wn2, w_out, we2,
        hwin, lwin, hwe1, lwe1, hwn1, lwn1, hwn2, lwn2, hwout, lwout, hwe2);
    k_embed_ab<<<128, 1024, 0, stream>>>(h, b_in, be1, hwin, lwin, hwe1, lwe1,
        xs_hi, xs_lo, A, Bb);
    for (int l = 0; l < NL; ++l) {
        const int last = (l == NL - 1);
        const int lp = last ? 0 : (l + 1);
        k_edge_mfma<<<NTOT, 256, 0, stream>>>(A, Bb,
            hwe2 + (size_t)l * 2048 * 8,
            be2 + l * EHD, agg);
        k_node_ab<<<128, 1024, 0, stream>>>(agg,
            bn1 + l * HD, bn2 + l * HD, be1 + lp * EHD, b_out,
            hwn1 + (size_t)l * 12288 * 8, lwn1 + (size_t)l * 12288 * 8,
            hwn2 + (size_t)l * 8192 * 8, lwn2 + (size_t)l * 8192 * 8,
            hwe1 + (size_t)lp * 8192 * 8, lwe1 + (size_t)lp * 8192 * 8,
            hwout, lwout, xs_hi, xs_lo, A, Bb, outp, last);
    }
}